// Round 18
// baseline (19737.897 us; speedup 1.0000x reference)
//
#include <hip/hip_runtime.h>
#include <stdint.h>

#define N 2048
#define BATCH 8
#define NROWS (BATCH * N)   // 16384
#define CAPN 256            // shortlist capacity per row
#define LE 16               // LDS list entries per row (ranks 0..15)
#define INV 0xFFFFFFFFu

typedef unsigned long long u64;
typedef unsigned u32;
typedef unsigned short u16;

#define DEADK 0xFFFFFFFFFFFFFFFFull

// ---------------- DPP wave64 reductions -----------------------------------
__device__ __forceinline__ unsigned wave_umin_bcast(unsigned x) {
#define DPP_MIN(ctrl)                                                          \
  {                                                                            \
    unsigned t = (unsigned)__builtin_amdgcn_update_dpp((int)x, (int)x, ctrl,   \
                                                       0xf, 0xf, false);       \
    x = t < x ? t : x;                                                         \
  }
  DPP_MIN(0x111) DPP_MIN(0x112) DPP_MIN(0x114) DPP_MIN(0x118)
  DPP_MIN(0x142) DPP_MIN(0x143)
#undef DPP_MIN
  return (unsigned)__builtin_amdgcn_readlane((int)x, 63);
}

__device__ __forceinline__ unsigned wave_umax_bcast(unsigned x) {
#define DPP_MAX(ctrl)                                                          \
  {                                                                            \
    unsigned t = (unsigned)__builtin_amdgcn_update_dpp((int)x, (int)x, ctrl,   \
                                                       0xf, 0xf, false);       \
    x = t > x ? t : x;                                                         \
  }
  DPP_MAX(0x111) DPP_MAX(0x112) DPP_MAX(0x114) DPP_MAX(0x118)
  DPP_MAX(0x142) DPP_MAX(0x143)
#undef DPP_MAX
  return (unsigned)__builtin_amdgcn_readlane((int)x, 63);
}

#define DPP64_MIN(x, ctrl)                                                     \
  {                                                                            \
    u32 lo_ = (u32)(x), hi_ = (u32)((x) >> 32);                                \
    u32 tlo_ = (u32)__builtin_amdgcn_update_dpp((int)lo_, (int)lo_, (ctrl),    \
                                                0xf, 0xf, false);              \
    u32 thi_ = (u32)__builtin_amdgcn_update_dpp((int)hi_, (int)hi_, (ctrl),    \
                                                0xf, 0xf, false);              \
    u64 t_ = ((u64)thi_ << 32) | tlo_;                                         \
    x = t_ < x ? t_ : x;                                                       \
  }

__device__ __forceinline__ u64 wave_min64_l63(u64 x) {
  DPP64_MIN(x, 0x111) DPP64_MIN(x, 0x112) DPP64_MIN(x, 0x114)
  DPP64_MIN(x, 0x118) DPP64_MIN(x, 0x142) DPP64_MIN(x, 0x143)
  return x;
}

// Exact-order distance: ((dx*dx + dy*dy) + dz*dz), no FMA contraction, sqrtf.
#define DIST(qx, qy, qz, TX, TY, TZ, j, dout)                                  \
  do {                                                                         \
    _Pragma("clang fp contract(off)")                                          \
    float dx_ = (qx) - (TX)[j];                                                \
    float dy_ = (qy) - (TY)[j];                                                \
    float dz_ = (qz) - (TZ)[j];                                                \
    float s_ = dx_ * dx_ + dy_ * dy_ + dz_ * dz_;                              \
    dout = sqrtf(s_);                                                          \
  } while (0)

// ---------------- Phase 1a: tau-shortlist (proven R2-R17) ------------------
__global__ __launch_bounds__(256, 1)
void emd_shortlist_kernel(const float* __restrict__ pred,
                          const float* __restrict__ target,
                          u64* __restrict__ keys,
                          u32* __restrict__ cnts) {
    __shared__ float tx[N], ty[N], tz[N];
    const int b  = blockIdx.x >> 9;
    const int r0 = (blockIdx.x & 511) << 2;
    const float* tb = target + (size_t)b * N * 3;

    for (int idx = threadIdx.x; idx < 3 * N; idx += 256) {
        float v = tb[idx];
        int n = idx / 3, c = idx - 3 * n;
        if (c == 0) tx[n] = v; else if (c == 1) ty[n] = v; else tz[n] = v;
    }
    __syncthreads();

    const int wid = threadIdx.x >> 6, lane = threadIdx.x & 63;
    const int i = r0 + wid;
    const size_t row = (size_t)b * N + i;
    const float* pb = pred + row * 3;
    const float qx = pb[0], qy = pb[1], qz = pb[2];

    float d[32];
    float m = 3.4e38f;
    #pragma unroll
    for (int c = 0; c < 32; ++c) {
        const int j = (c << 6) + lane;
        float dd;
        DIST(qx, qy, qz, tx, ty, tz, j, dd);
        d[c] = dd;
        m = fminf(m, dd);
    }

    unsigned mb = __float_as_uint(m);
    {   // pair-min (xor1 quad_perm): tau = max of 32 min-of-64 -> E[cnt]~130
        unsigned t = (unsigned)__builtin_amdgcn_update_dpp((int)mb, (int)mb,
                                                           0x0B1, 0xf, 0xf, false);
        mb = t < mb ? t : mb;
    }
    const unsigned tau = wave_umax_bcast(mb);
    const float tauf = __uint_as_float(tau);

    u64* krow = keys + row * (size_t)CAPN;
    unsigned base = 0;
    #pragma unroll
    for (int c = 0; c < 32; ++c) {
        const bool p = d[c] <= tauf;
        const u64 bm = __ballot(p);
        if (p) {
            unsigned off = base + (unsigned)__popcll(bm & ((1ull << lane) - 1ull));
            if (off < (unsigned)CAPN)
                krow[off] = ((u64)__float_as_uint(d[c]) << 32) |
                            (unsigned)((c << 6) + lane);
        }
        base += (unsigned)__popcll(bm);
    }
    if (lane == 0) cnts[row] = base;
}

// ---------------- Phase 1b: in-place sorted top-16 extraction --------------
// (only ranks 0..15 are consumed; ranks beyond are handled by scan mode)
#define CSWAP(a, b)                                                            \
  { u64 mn_ = (a) < (b) ? (a) : (b); u64 mx_ = (a) < (b) ? (b) : (a);          \
    (a) = mn_; (b) = mx_; }

__global__ __launch_bounds__(256, 1)
void emd_sort16_kernel(u64* __restrict__ keys, const u32* __restrict__ cnts) {
    const int wid = threadIdx.x >> 6, lane = threadIdx.x & 63;
    const size_t row = (size_t)blockIdx.x * 4 + wid;
    u64* krow = keys + row * (size_t)CAPN;

    const u32 cnt = cnts[row];
    const u32 lim = (cnt > (u32)CAPN) ? 0u : cnt;   // overflow -> no candidates

    u64 k0 = ((u32)lane       < lim) ? krow[lane      ] : DEADK;
    u64 k1 = ((u32)lane + 64  < lim) ? krow[lane + 64 ] : DEADK;
    u64 k2 = ((u32)lane + 128 < lim) ? krow[lane + 128] : DEADK;
    u64 k3 = ((u32)lane + 192 < lim) ? krow[lane + 192] : DEADK;

    CSWAP(k0, k1) CSWAP(k2, k3) CSWAP(k0, k2) CSWAP(k1, k3) CSWAP(k1, k2)

    u64 mykey = DEADK;
    for (int it = 0; it < LE; ++it) {
        u64 wm = wave_min64_l63(k0);
        u32 wlo = (u32)__builtin_amdgcn_readlane((int)(u32)wm, 63);
        u32 whi = (u32)__builtin_amdgcn_readlane((int)(u32)(wm >> 32), 63);
        if (whi == 0xFFFFFFFFu) break;            // all exhausted (cnt < LE)
        const u64 wkey = ((u64)whi << 32) | wlo;
        mykey = (lane == it) ? wkey : mykey;      // capture in lane `it`
        const bool eq = (k0 == wkey);             // unique (distinct j)
        k0 = eq ? k1 : k0; k1 = eq ? k2 : k1; k2 = eq ? k3 : k2;
        k3 = eq ? DEADK : k3;
    }
    krow[lane] = mykey;   // lanes >= LE (or past cnt) hold DEADK
}

// ---------------- Phase 2: da8 — pure thread-walk DA, no stage 2 -----------
// THEOREM (HW-validated R9-R17, absmax 0.0): greedy row-order matching ==
// unique stable matching == row-proposing DA under ANY proposal order;
// holder[] via atomicMin monotone => rejections permanent; proposing to the
// best target in {j: holder[j] > r} == DA with doomed-proposal skipping
// (stale holder reads only over-include; atomicMin re-verifies; lost race
// => rescan over a strictly-shrunk set).
// R17 diag: stage-2 queue machinery duplicated work (hops >= 320k > the 131k
// bound) and was unstable (28ms outlier). da8 DELETES stage 2: each of 2048
// chains is walked start-to-finish by one thread -- ranks 0..15 from LDS
// list16 (measured ~25us for ~15k proposals, R14), rank>=16 via an INLINE
// per-thread scalar scan (min (d,j) over {holder>r} from LDS coords).
// Adoption stays in-lane; displaced scan-mode rows rescan. Chain row-indices
// strictly increase => termination; ONE barrier; no queues, no polling.
__global__ __launch_bounds__(1024, 1)
void emd_da8_kernel(const float* __restrict__ pred,
                    const float* __restrict__ target,
                    const u64* __restrict__ keys,
                    float* __restrict__ batch_emd) {
    __shared__ float tx[N], ty[N], tz[N];        // 24KB targets
    __shared__ float px[N], py[N], pz[N];        // 24KB preds
    __shared__ u32 holder[N];                    // 8KB
    __shared__ u16 posn[N];                      // 4KB
    __shared__ u16 list16[N * LE];               // 64KB ranks 0..15
    __shared__ double dsum[16];

    const int tid = threadIdx.x;
    const int lane = tid & 63;
    const int b = blockIdx.x;
    const float* pb = pred + (size_t)b * N * 3;
    const float* tb = target + (size_t)b * N * 3;
    const u64* kb = keys + (size_t)b * N * (size_t)CAPN;

    // ---- setup ----
    for (int idx = tid; idx < 3 * N; idx += 1024) {
        float vp = pb[idx], vt = tb[idx];
        int n = idx / 3, c = idx - 3 * n;
        if (c == 0)      { px[n] = vp; tx[n] = vt; }
        else if (c == 1) { py[n] = vp; ty[n] = vt; }
        else             { pz[n] = vp; tz[n] = vt; }
    }
    for (int j = tid; j < N; j += 1024) { holder[j] = INV; posn[j] = 0; }
    for (int idx = tid; idx < N * LE; idx += 1024) {
        const int row = idx >> 4, e = idx & (LE - 1);
        const u64 key = kb[(size_t)row * CAPN + e];
        list16[idx] = ((u32)(key >> 32) == INV) ? (u16)0xFFFF
                                                : (u16)((u32)key & (N - 1));
    }
    __syncthreads();

    // ---- the walks: 2 chains per thread, everything in-lane ----
    #pragma unroll
    for (int k = 0; k < 2; ++k) {
        u32 r = (u32)tid + (k ? 1024u : 0u);
        u32 p = 0;
        for (int guard = 0; guard < 1000000; ++guard) {
            if (p < LE) {
                // list walk (ranks 0..15)
                const u32 t = (u32)list16[(r << 4) + p];
                if (t == 0xFFFFu) { p = LE; continue; }      // -> scan mode
                if (holder[t] < r) { ++p; continue; }        // pre-reject
                const u32 old = atomicMin(&holder[t], r);
                if (old < r) { ++p; continue; }              // rejected
                posn[r] = (u16)(p + 1);                      // held
                if (old == INV) break;                       // chain done
                r = old; p = (u32)posn[r];                   // ADOPT
                continue;
            }
            // scan mode (rank >= LE): exact best over {j: holder[j] > r}
            posn[r] = 64;                // adopters of r must rescan
            const float qx = px[r], qy = py[r], qz = pz[r];
            u32 old = 0;
            for (int rty = 0; rty < 10000; ++rty) {
                u64 best = DEADK;
                #pragma unroll 4
                for (int j = 0; j < N; ++j) {
                    if (holder[j] > r) {
                        float dd;
                        DIST(qx, qy, qz, tx, ty, tz, j, dd);
                        const u64 kk = ((u64)__float_as_uint(dd) << 32) | (u32)j;
                        if (kk < best) best = kk;
                    }
                }
                const u32 t = (u32)best & (N - 1);
                old = atomicMin(&holder[t], r);
                if (old >= r) break;     // held (INV free or displaced old>r)
                // lost race: candidate set shrank, rescan
            }
            if (old == INV) break;       // chain done
            r = old; p = (u32)posn[r];   // ADOPT (p may be <16 or 64)
        }
    }
    __syncthreads();

    // ---- final sum over targets (recomputed DIST bit-identical to keys) ---
    double s = 0.0;
    #pragma unroll
    for (int k = 0; k < 2; ++k) {
        const int t = tid + (k ? 1024 : 0);
        const u32 r = holder[t] & (N - 1);
        float dd;
        DIST(px[r], py[r], pz[r], tx, ty, tz, t, dd);
        s += (double)dd;
    }
    #pragma unroll
    for (int m = 32; m >= 1; m >>= 1) s += __shfl_down(s, m, 64);
    if (lane == 0) dsum[tid >> 6] = s;
    __syncthreads();
    if (tid == 0) {
        double tot = 0.0;
        #pragma unroll
        for (int w = 0; w < 16; ++w) tot += dsum[w];
        batch_emd[b] = (float)(tot / N);
    }
}

// ---------------- exact full-scan helper (tiny-ws fallback kernel) --------
__device__ __forceinline__ u64 full_scan_row(
    int lane, float qx, float qy, float qz,
    const float* tx, const float* ty, const float* tz,
    const unsigned char* used) {
  u32 dl = 0xFFFFFFFFu, jl = 0u;
  #pragma unroll 8
  for (int c = 0; c < 32; ++c) {
    const int j = (c << 6) + lane;
    if (!used[j]) {
      float dd;
      DIST(qx, qy, qz, tx, ty, tz, j, dd);
      const u32 db = __float_as_uint(dd);
      if (db < dl) { dl = db; jl = (u32)j; }
    }
  }
  const u32 dmin = wave_umin_bcast(dl);
  const u32 jc = (dl == dmin) ? jl : 0xFFFFFFFFu;
  const u32 jmin = wave_umin_bcast(jc);
  return ((u64)dmin << 32) | jmin;
}

__global__ __launch_bounds__(64, 1)
void emd_greedy_full_kernel(const float* __restrict__ pred,
                            const float* __restrict__ target,
                            float* __restrict__ batch_emd) {
    __shared__ float tx[N], ty[N], tz[N];
    __shared__ float qxs[N], qys[N], qzs[N];
    __shared__ unsigned char used[N];

    const int lane = threadIdx.x;
    const int b = blockIdx.x;
    const float* pb = pred + (size_t)b * N * 3;
    const float* tb = target + (size_t)b * N * 3;

    for (int idx = lane; idx < 3 * N; idx += 64) {
        float vp = pb[idx], vt = tb[idx];
        int n = idx / 3, c = idx - 3 * n;
        if (c == 0)      { qxs[n] = vp; tx[n] = vt; }
        else if (c == 1) { qys[n] = vp; ty[n] = vt; }
        else             { qzs[n] = vp; tz[n] = vt; }
    }
    for (int j = lane; j < N; j += 64) used[j] = 0;

    double sum = 0.0;
    for (int i = 0; i < N; ++i) {
        u64 fs = full_scan_row(lane, qxs[i], qys[i], qzs[i], tx, ty, tz, used);
        sum += (double)__uint_as_float((u32)(fs >> 32));
        if (lane == 0) used[(u32)fs] = 1;
    }
    if (lane == 0) batch_emd[b] = (float)(sum / N);
}

__global__ void emd_mean_kernel(const float* __restrict__ batch_emd,
                                float* __restrict__ out) {
    double s = 0.0;
    for (int b = 0; b < BATCH; ++b) s += (double)batch_emd[b];
    out[0] = (float)(s / BATCH);
}

extern "C" void kernel_launch(void* const* d_in, const int* in_sizes, int n_in,
                              void* d_out, int out_size, void* d_ws, size_t ws_size,
                              hipStream_t stream) {
    const float* pred   = (const float*)d_in[0];
    const float* target = (const float*)d_in[1];
    float* out = (float*)d_out;
    char* wsb = (char*)d_ws;

    const size_t keysz = (size_t)NROWS * CAPN * 8;   // 33.6 MB
    const size_t cntsz = (size_t)NROWS * 4;

    if (ws_size >= keysz + cntsz + 64) {
        u64* keys = (u64*)wsb;
        u32* cnts = (u32*)(wsb + keysz);
        float* emd = (float*)(wsb + keysz + cntsz);
        emd_shortlist_kernel<<<NROWS / 4, 256, 0, stream>>>(pred, target, keys, cnts);
        emd_sort16_kernel<<<NROWS / 4, 256, 0, stream>>>(keys, cnts);
        emd_da8_kernel<<<BATCH, 1024, 0, stream>>>(pred, target, keys, emd);
        emd_mean_kernel<<<1, 1, 0, stream>>>(emd, out);
    } else {
        float* emd = (float*)wsb;
        emd_greedy_full_kernel<<<BATCH, 64, 0, stream>>>(pred, target, emd);
        emd_mean_kernel<<<1, 1, 0, stream>>>(emd, out);
    }
}

// Round 19
// 550.104 us; speedup vs baseline: 35.8803x; 35.8803x over previous
//
#include <hip/hip_runtime.h>
#include <stdint.h>

#define N 2048
#define BATCH 8
#define NROWS (BATCH * N)   // 16384
#define K64 64              // stored sorted candidates per row
#define LE 16               // LDS list entries per row in DA (ranks 0..15)
#define EXQ 2048            // event ring (>= max pushes)
#define INV 0xFFFFFFFFu

typedef unsigned long long u64;
typedef unsigned u32;
typedef unsigned short u16;

#define DEADK 0xFFFFFFFFFFFFFFFFull

// ---------------- DPP wave64 reductions -----------------------------------
__device__ __forceinline__ unsigned wave_umin_bcast(unsigned x) {
#define DPP_MIN(ctrl)                                                          \
  {                                                                            \
    unsigned t = (unsigned)__builtin_amdgcn_update_dpp((int)x, (int)x, ctrl,   \
                                                       0xf, 0xf, false);       \
    x = t < x ? t : x;                                                         \
  }
  DPP_MIN(0x111) DPP_MIN(0x112) DPP_MIN(0x114) DPP_MIN(0x118)
  DPP_MIN(0x142) DPP_MIN(0x143)
#undef DPP_MIN
  return (unsigned)__builtin_amdgcn_readlane((int)x, 63);
}

__device__ __forceinline__ unsigned wave_umax_bcast(unsigned x) {
#define DPP_MAX(ctrl)                                                          \
  {                                                                            \
    unsigned t = (unsigned)__builtin_amdgcn_update_dpp((int)x, (int)x, ctrl,   \
                                                       0xf, 0xf, false);       \
    x = t > x ? t : x;                                                         \
  }
  DPP_MAX(0x111) DPP_MAX(0x112) DPP_MAX(0x114) DPP_MAX(0x118)
  DPP_MAX(0x142) DPP_MAX(0x143)
#undef DPP_MAX
  return (unsigned)__builtin_amdgcn_readlane((int)x, 63);
}

#define DPP64_MIN(x, ctrl)                                                     \
  {                                                                            \
    u32 lo_ = (u32)(x), hi_ = (u32)((x) >> 32);                                \
    u32 tlo_ = (u32)__builtin_amdgcn_update_dpp((int)lo_, (int)lo_, (ctrl),    \
                                                0xf, 0xf, false);              \
    u32 thi_ = (u32)__builtin_amdgcn_update_dpp((int)hi_, (int)hi_, (ctrl),    \
                                                0xf, 0xf, false);              \
    u64 t_ = ((u64)thi_ << 32) | tlo_;                                         \
    x = t_ < x ? t_ : x;                                                       \
  }

__device__ __forceinline__ u64 wave_min64_l63(u64 x) {
  DPP64_MIN(x, 0x111) DPP64_MIN(x, 0x112) DPP64_MIN(x, 0x114)
  DPP64_MIN(x, 0x118) DPP64_MIN(x, 0x142) DPP64_MIN(x, 0x143)
  return x;
}

// Exact-order distance: ((dx*dx + dy*dy) + dz*dz), no FMA contraction, sqrtf.
#define DIST(qx, qy, qz, TX, TY, TZ, j, dout)                                  \
  do {                                                                         \
    _Pragma("clang fp contract(off)")                                          \
    float dx_ = (qx) - (TX)[j];                                                \
    float dy_ = (qy) - (TY)[j];                                                \
    float dz_ = (qz) - (TZ)[j];                                                \
    float s_ = dx_ * dx_ + dy_ * dy_ + dz_ * dz_;                              \
    dout = sqrtf(s_);                                                          \
  } while (0)

// ---------------- Phase 1 (FUSED): tau-shortlist -> sorted top-64 ----------
// Per wave (1 row): compute d[32], tau = wave-max of lane-pair minima
// (guarantees >=32 candidates <= tau; {d <= tau} prefix-closed under (d,j)),
// compact tau-set into per-wave LDS scratch, sort-extract top-64 in-register,
// write ONLY the top-64 keys (global, stride K64). Replaces R2-R18's separate
// 1a (17MB global write) + 1b (reload+sort) -- same math, verified absmax 0.0.
__global__ __launch_bounds__(256, 1)
void emd_shortsort_kernel(const float* __restrict__ pred,
                          const float* __restrict__ target,
                          u64* __restrict__ keys) {
    __shared__ float tx[N], ty[N], tz[N];        // 24KB
    __shared__ u64 cand[4 * 256];                // 8KB per-wave scratch

    const int b  = blockIdx.x >> 9;
    const int r0 = (blockIdx.x & 511) << 2;
    const float* tb = target + (size_t)b * N * 3;

    for (int idx = threadIdx.x; idx < 3 * N; idx += 256) {
        float v = tb[idx];
        int n = idx / 3, c = idx - 3 * n;
        if (c == 0) tx[n] = v; else if (c == 1) ty[n] = v; else tz[n] = v;
    }
    __syncthreads();

    const int wid = threadIdx.x >> 6, lane = threadIdx.x & 63;
    const int i = r0 + wid;
    const size_t row = (size_t)b * N + i;
    const float* pb = pred + row * 3;
    const float qx = pb[0], qy = pb[1], qz = pb[2];

    float d[32];
    float m = 3.4e38f;
    #pragma unroll
    for (int c = 0; c < 32; ++c) {
        const int j = (c << 6) + lane;
        float dd;
        DIST(qx, qy, qz, tx, ty, tz, j, dd);
        d[c] = dd;
        m = fminf(m, dd);
    }

    unsigned mb = __float_as_uint(m);
    {   // pair-min (xor1 quad_perm): tau = max of 32 min-of-64 -> E[cnt]~130
        unsigned t = (unsigned)__builtin_amdgcn_update_dpp((int)mb, (int)mb,
                                                           0x0B1, 0xf, 0xf, false);
        mb = t < mb ? t : mb;
    }
    const unsigned tau = wave_umax_bcast(mb);
    const float tauf = __uint_as_float(tau);

    // compact tau-set into this wave's LDS scratch (ascending-j order)
    u64* cw = cand + wid * 256;
    unsigned base = 0;
    #pragma unroll
    for (int c = 0; c < 32; ++c) {
        const bool p = d[c] <= tauf;
        const u64 bm = __ballot(p);
        if (p) {
            unsigned off = base + (unsigned)__popcll(bm & ((1ull << lane) - 1ull));
            if (off < 256u)
                cw[off] = ((u64)__float_as_uint(d[c]) << 32) |
                          (unsigned)((c << 6) + lane);
        }
        base += (unsigned)__popcll(bm);
    }
    // single wave region: LDS program-ordered, no barrier needed
    const u32 lim = (base > 256u) ? 0u : base;   // overflow -> all DEADK

    u64 k0 = ((u32)lane       < lim) ? cw[lane      ] : DEADK;
    u64 k1 = ((u32)lane + 64  < lim) ? cw[lane + 64 ] : DEADK;
    u64 k2 = ((u32)lane + 128 < lim) ? cw[lane + 128] : DEADK;
    u64 k3 = ((u32)lane + 192 < lim) ? cw[lane + 192] : DEADK;

#define CSWAP(a, b)                                                            \
  { u64 mn_ = (a) < (b) ? (a) : (b); u64 mx_ = (a) < (b) ? (b) : (a);          \
    (a) = mn_; (b) = mx_; }
    CSWAP(k0, k1) CSWAP(k2, k3) CSWAP(k0, k2) CSWAP(k1, k3) CSWAP(k1, k2)
#undef CSWAP

    u64 mykey = DEADK;
    for (int it = 0; it < K64; ++it) {
        u64 wm = wave_min64_l63(k0);
        u32 wlo = (u32)__builtin_amdgcn_readlane((int)(u32)wm, 63);
        u32 whi = (u32)__builtin_amdgcn_readlane((int)(u32)(wm >> 32), 63);
        if (whi == 0xFFFFFFFFu) break;            // exhausted (cnt < 64)
        const u64 wkey = ((u64)whi << 32) | wlo;
        mykey = (lane == it) ? wkey : mykey;      // capture in lane `it`
        const bool eq = (k0 == wkey);             // unique (distinct j)
        k0 = eq ? k1 : k0; k1 = eq ? k2 : k1; k2 = eq ? k3 : k2;
        k3 = eq ? DEADK : k3;
    }
    keys[row * (size_t)K64 + lane] = mykey;       // lane-th smallest / DEADK
}

// ---------------- Phase 2: da5 (R15-verified), keys stride K64 -------------
// THEOREM (HW-validated R9-R18, absmax 0.0): greedy row-order matching ==
// unique stable matching == row-proposing DA under ANY proposal order;
// holder[] via atomicMin monotone => rejections permanent.
// Stage 1: 2048 all-LDS per-thread walks with in-lane adoption (~25us).
// Stage 2: frozen event list; scalar list-walk hops; wave-level global
// top-64 resume / full-LDS scan for deep rows. (456-467us across four
// structurally different stage-2 variants -- endgame-serialization wall.)
__global__ __launch_bounds__(1024, 1)
void emd_da5_kernel(const float* __restrict__ pred,
                    const float* __restrict__ target,
                    const u64* __restrict__ keys,
                    float* __restrict__ batch_emd) {
    __shared__ float tx[N], ty[N], tz[N];        // 24KB targets
    __shared__ float px[N], py[N], pz[N];        // 24KB preds
    __shared__ u32 holder[N];                    // 8KB
    __shared__ u16 posn[N];                      // 4KB
    __shared__ u16 list16[N * LE];               // 64KB u16 target lists
    __shared__ u16 exq[EXQ];                     // 4KB event ring
    __shared__ u32 talloc, head;
    __shared__ double dsum[1024];                // 8KB

    const int tid = threadIdx.x;
    const int lane = tid & 63;
    const int b = blockIdx.x;
    const float* pb = pred + (size_t)b * N * 3;
    const float* tb = target + (size_t)b * N * 3;
    const u64* kb = keys + (size_t)b * N * (size_t)K64;

    // ---- setup ----
    for (int idx = tid; idx < 3 * N; idx += 1024) {
        float vp = pb[idx], vt = tb[idx];
        int n = idx / 3, c = idx - 3 * n;
        if (c == 0)      { px[n] = vp; tx[n] = vt; }
        else if (c == 1) { py[n] = vp; ty[n] = vt; }
        else             { pz[n] = vp; tz[n] = vt; }
    }
    for (int j = tid; j < N; j += 1024) { holder[j] = INV; posn[j] = 0; }
    if (tid == 0) { talloc = 0; head = 0; }
    for (int idx = tid; idx < N * LE; idx += 1024) {
        const int row = idx >> 4, e = idx & (LE - 1);
        const u64 key = kb[(size_t)row * K64 + e];
        list16[idx] = ((u32)(key >> 32) == INV) ? (u16)0xFFFF
                                                : (u16)((u32)key & (N - 1));
    }
    __syncthreads();

    // ---- stage 1: all-LDS per-thread walks with adoption ----
    #pragma unroll
    for (int k = 0; k < 2; ++k) {
        u32 r = (u32)tid + (k ? 1024u : 0u);
        u32 p = 0;
        for (int guard = 0; guard < 200000; ++guard) {
            if (p >= LE) {              // deep walk -> defer to stage 2
                posn[r] = LE;           // 0..15 permanently rejected
                const u32 s = atomicAdd(&talloc, 1u);
                exq[s & (EXQ - 1)] = (u16)r;
                break;
            }
            const u32 t = (u32)list16[(r << 4) + p];
            if (t == 0xFFFFu) {         // sorted list ended (overflow row)
                posn[r] = 64;
                const u32 s = atomicAdd(&talloc, 1u);
                exq[s & (EXQ - 1)] = (u16)r;
                break;
            }
            const u32 old = atomicMin(&holder[t], r);
            if (old < r) { ++p; continue; }          // rejected (permanent)
            posn[r] = (u16)(p + 1);                  // held
            if (old == INV) break;                   // free target: chain done
            r = old; p = (u32)posn[r];               // ADOPT displaced row
        }
    }
    __syncthreads();

    // ---- stage 2: frozen event list; scalar hops, wave-level deep path ----
    {
        const u32 TA = talloc;          // frozen: stage 2 never pushes
        for (int guard = 0; guard < 20000; ++guard) {
            u32 i = 0;
            if (lane == 0) i = atomicAdd(&head, 1u);
            i = (u32)__builtin_amdgcn_readlane((int)i, 0);
            if (i >= TA) break;
            u32 r = (u32)exq[i & (EXQ - 1)];         // uniform LDS read

            for (int cg = 0; cg < 200000; ++cg) {    // cascade with adoption
                u32 p = (u32)posn[r];                // uniform
                u32 nextr = INV;
                bool matched_free = false, resolved = false;

                // A) SCALAR walk over list16 entries p..15
                if (p < LE) {
                    bool deep = false;
                    for (int w = 0; w < 64; ++w) {
                        if (p >= LE) { deep = true; break; }
                        const u32 t = (u32)list16[(r << 4) + p];
                        if (t == 0xFFFFu) { p = 64; break; }   // dead suffix
                        if (holder[t] < r) { ++p; continue; }  // pre-reject
                        u32 old = 0;
                        if (lane == 0) old = atomicMin(&holder[t], r);
                        old = (u32)__builtin_amdgcn_readlane((int)old, 0);
                        if (old < r) { ++p; continue; }        // rejected
                        if (lane == 0) posn[r] = (u16)(p + 1);
                        resolved = true;
                        if (old == INV) matched_free = true; else nextr = old;
                        break;
                    }
                    if (!resolved) {
                        if (deep) p = LE;
                        if (lane == 0) posn[r] = (u16)p;
                    }
                }

                // B) wave-level global top-64 resume: entries p..63
                if (!resolved && p < 64) {
                    const u64 key = kb[(size_t)r * K64 + lane];
                    const u32 dv = (u32)(key >> 32);
                    const u32 t = (u32)key & (N - 1);
                    const bool cand = ((u32)lane >= p) && (dv != INV) &&
                                      (holder[t] > r);
                    u64 bal = __ballot(cand);
                    while (bal) {                    // propose in list order
                        const int L = __ffsll((long long)bal) - 1;
                        const u32 tL = (u32)__builtin_amdgcn_readlane((int)t, L);
                        u32 old = 0;
                        if (lane == 0) old = atomicMin(&holder[tL], r);
                        old = (u32)__builtin_amdgcn_readlane((int)old, 0);
                        if (old > r) {
                            if (lane == 0) posn[r] = (u16)(L + 1);
                            resolved = true;
                            if (old == INV) matched_free = true;
                            else nextr = old;
                            break;
                        }
                        bal &= ~(1ull << (u32)L);    // raced: permanent
                    }
                }

                // C) wave-level full scan over {j: holder[j]>r}; DISTs hoisted
                if (!resolved) {
                    const float qx = px[r], qy = py[r], qz = pz[r];
                    u32 dbits[32];
                    #pragma unroll
                    for (int c = 0; c < 32; ++c) {
                        const int j = (c << 6) + lane;
                        float dd;
                        DIST(qx, qy, qz, tx, ty, tz, j, dd);
                        dbits[c] = __float_as_uint(dd);
                    }
                    for (int rty = 0; rty < 100000; ++rty) {
                        u64 best = DEADK;
                        #pragma unroll 8
                        for (int c = 0; c < 32; ++c) {
                            const int j = (c << 6) + lane;
                            if (holder[j] > r) {
                                const u64 kk = ((u64)dbits[c] << 32) | (u32)j;
                                if (kk < best) best = kk;
                            }
                        }
                        const u64 wm = wave_min64_l63(best);
                        const u32 jw =
                            (u32)__builtin_amdgcn_readlane((int)(u32)wm, 63) &
                            (N - 1);
                        u32 old = 0;
                        if (lane == 0) old = atomicMin(&holder[jw], r);
                        old = (u32)__builtin_amdgcn_readlane((int)old, 0);
                        if (old < r) continue;       // lost race: set shrank
                        if (lane == 0) posn[r] = 64;
                        if (old == INV) matched_free = true; else nextr = old;
                        break;
                    }
                }

                if (matched_free) break;             // cascade ended
                r = nextr;                           // adopt, continue
            }
        }
    }
    __syncthreads();

    // ---- final sum over targets (recomputed DIST bit-identical to keys) ---
    double s = 0.0;
    #pragma unroll
    for (int k = 0; k < 2; ++k) {
        const int t = tid + (k ? 1024 : 0);
        const u32 r = holder[t] & (N - 1);
        float dd;
        DIST(px[r], py[r], pz[r], tx, ty, tz, t, dd);
        s += (double)dd;
    }
    dsum[tid] = s;
    __syncthreads();
    for (int st = 512; st >= 1; st >>= 1) {
        if (tid < st) dsum[tid] += dsum[tid + st];
        __syncthreads();
    }
    if (tid == 0) batch_emd[b] = (float)(dsum[0] / N);
}

// ---------------- exact full-scan helper (tiny-ws fallback kernel) --------
__device__ __forceinline__ u64 full_scan_row(
    int lane, float qx, float qy, float qz,
    const float* tx, const float* ty, const float* tz,
    const unsigned char* used) {
  u32 dl = 0xFFFFFFFFu, jl = 0u;
  #pragma unroll 8
  for (int c = 0; c < 32; ++c) {
    const int j = (c << 6) + lane;
    if (!used[j]) {
      float dd;
      DIST(qx, qy, qz, tx, ty, tz, j, dd);
      const u32 db = __float_as_uint(dd);
      if (db < dl) { dl = db; jl = (u32)j; }
    }
  }
  const u32 dmin = wave_umin_bcast(dl);
  const u32 jc = (dl == dmin) ? jl : 0xFFFFFFFFu;
  const u32 jmin = wave_umin_bcast(jc);
  return ((u64)dmin << 32) | jmin;
}

__global__ __launch_bounds__(64, 1)
void emd_greedy_full_kernel(const float* __restrict__ pred,
                            const float* __restrict__ target,
                            float* __restrict__ batch_emd) {
    __shared__ float tx[N], ty[N], tz[N];
    __shared__ float qxs[N], qys[N], qzs[N];
    __shared__ unsigned char used[N];

    const int lane = threadIdx.x;
    const int b = blockIdx.x;
    const float* pb = pred + (size_t)b * N * 3;
    const float* tb = target + (size_t)b * N * 3;

    for (int idx = lane; idx < 3 * N; idx += 64) {
        float vp = pb[idx], vt = tb[idx];
        int n = idx / 3, c = idx - 3 * n;
        if (c == 0)      { qxs[n] = vp; tx[n] = vt; }
        else if (c == 1) { qys[n] = vp; ty[n] = vt; }
        else             { qzs[n] = vp; tz[n] = vt; }
    }
    for (int j = lane; j < N; j += 64) used[j] = 0;

    double sum = 0.0;
    for (int i = 0; i < N; ++i) {
        u64 fs = full_scan_row(lane, qxs[i], qys[i], qzs[i], tx, ty, tz, used);
        sum += (double)__uint_as_float((u32)(fs >> 32));
        if (lane == 0) used[(u32)fs] = 1;
    }
    if (lane == 0) batch_emd[b] = (float)(sum / N);
}

__global__ void emd_mean_kernel(const float* __restrict__ batch_emd,
                                float* __restrict__ out) {
    double s = 0.0;
    for (int b = 0; b < BATCH; ++b) s += (double)batch_emd[b];
    out[0] = (float)(s / BATCH);
}

extern "C" void kernel_launch(void* const* d_in, const int* in_sizes, int n_in,
                              void* d_out, int out_size, void* d_ws, size_t ws_size,
                              hipStream_t stream) {
    const float* pred   = (const float*)d_in[0];
    const float* target = (const float*)d_in[1];
    float* out = (float*)d_out;
    char* wsb = (char*)d_ws;

    const size_t keysz = (size_t)NROWS * K64 * 8;   // 8.4 MB
    if (ws_size >= keysz + 64) {
        u64* keys = (u64*)wsb;
        float* emd = (float*)(wsb + keysz);
        emd_shortsort_kernel<<<NROWS / 4, 256, 0, stream>>>(pred, target, keys);
        emd_da5_kernel<<<BATCH, 1024, 0, stream>>>(pred, target, keys, emd);
        emd_mean_kernel<<<1, 1, 0, stream>>>(emd, out);
    } else {
        float* emd = (float*)wsb;
        emd_greedy_full_kernel<<<BATCH, 64, 0, stream>>>(pred, target, emd);
        emd_mean_kernel<<<1, 1, 0, stream>>>(emd, out);
    }
}

// Round 20
// 526.756 us; speedup vs baseline: 37.4707x; 1.0443x over previous
//
#include <hip/hip_runtime.h>
#include <stdint.h>

#define N 2048
#define BATCH 8
#define NROWS (BATCH * N)   // 16384
#define K64 64              // stored sorted candidates per row
#define LE 16               // LDS list entries per row in DA (ranks 0..15)
#define EXQ 2048            // event ring (>= max pushes)
#define INV 0xFFFFFFFFu

typedef unsigned long long u64;
typedef unsigned u32;
typedef unsigned short u16;

#define DEADK 0xFFFFFFFFFFFFFFFFull

// ---------------- DPP wave64 reductions -----------------------------------
__device__ __forceinline__ unsigned wave_umin_bcast(unsigned x) {
#define DPP_MIN(ctrl)                                                          \
  {                                                                            \
    unsigned t = (unsigned)__builtin_amdgcn_update_dpp((int)x, (int)x, ctrl,   \
                                                       0xf, 0xf, false);       \
    x = t < x ? t : x;                                                         \
  }
  DPP_MIN(0x111) DPP_MIN(0x112) DPP_MIN(0x114) DPP_MIN(0x118)
  DPP_MIN(0x142) DPP_MIN(0x143)
#undef DPP_MIN
  return (unsigned)__builtin_amdgcn_readlane((int)x, 63);
}

__device__ __forceinline__ unsigned wave_umax_bcast(unsigned x) {
#define DPP_MAX(ctrl)                                                          \
  {                                                                            \
    unsigned t = (unsigned)__builtin_amdgcn_update_dpp((int)x, (int)x, ctrl,   \
                                                       0xf, 0xf, false);       \
    x = t > x ? t : x;                                                         \
  }
  DPP_MAX(0x111) DPP_MAX(0x112) DPP_MAX(0x114) DPP_MAX(0x118)
  DPP_MAX(0x142) DPP_MAX(0x143)
#undef DPP_MAX
  return (unsigned)__builtin_amdgcn_readlane((int)x, 63);
}

#define DPP64_MIN(x, ctrl)                                                     \
  {                                                                            \
    u32 lo_ = (u32)(x), hi_ = (u32)((x) >> 32);                                \
    u32 tlo_ = (u32)__builtin_amdgcn_update_dpp((int)lo_, (int)lo_, (ctrl),    \
                                                0xf, 0xf, false);              \
    u32 thi_ = (u32)__builtin_amdgcn_update_dpp((int)hi_, (int)hi_, (ctrl),    \
                                                0xf, 0xf, false);              \
    u64 t_ = ((u64)thi_ << 32) | tlo_;                                         \
    x = t_ < x ? t_ : x;                                                       \
  }

__device__ __forceinline__ u64 wave_min64_l63(u64 x) {
  DPP64_MIN(x, 0x111) DPP64_MIN(x, 0x112) DPP64_MIN(x, 0x114)
  DPP64_MIN(x, 0x118) DPP64_MIN(x, 0x142) DPP64_MIN(x, 0x143)
  return x;
}

// Exact-order distance: ((dx*dx + dy*dy) + dz*dz), no FMA contraction, sqrtf.
#define DIST(qx, qy, qz, TX, TY, TZ, j, dout)                                  \
  do {                                                                         \
    _Pragma("clang fp contract(off)")                                          \
    float dx_ = (qx) - (TX)[j];                                                \
    float dy_ = (qy) - (TY)[j];                                                \
    float dz_ = (qz) - (TZ)[j];                                                \
    float s_ = dx_ * dx_ + dy_ * dy_ + dz_ * dz_;                              \
    dout = sqrtf(s_);                                                          \
  } while (0)

// ---------------- Phase 1 (FUSED): tau-shortlist -> sorted top-64 ----------
// (verified R19, absmax 0.0)
__global__ __launch_bounds__(256, 1)
void emd_shortsort_kernel(const float* __restrict__ pred,
                          const float* __restrict__ target,
                          u64* __restrict__ keys) {
    __shared__ float tx[N], ty[N], tz[N];        // 24KB
    __shared__ u64 cand[4 * 256];                // 8KB per-wave scratch

    const int b  = blockIdx.x >> 9;
    const int r0 = (blockIdx.x & 511) << 2;
    const float* tb = target + (size_t)b * N * 3;

    for (int idx = threadIdx.x; idx < 3 * N; idx += 256) {
        float v = tb[idx];
        int n = idx / 3, c = idx - 3 * n;
        if (c == 0) tx[n] = v; else if (c == 1) ty[n] = v; else tz[n] = v;
    }
    __syncthreads();

    const int wid = threadIdx.x >> 6, lane = threadIdx.x & 63;
    const int i = r0 + wid;
    const size_t row = (size_t)b * N + i;
    const float* pb = pred + row * 3;
    const float qx = pb[0], qy = pb[1], qz = pb[2];

    float d[32];
    float m = 3.4e38f;
    #pragma unroll
    for (int c = 0; c < 32; ++c) {
        const int j = (c << 6) + lane;
        float dd;
        DIST(qx, qy, qz, tx, ty, tz, j, dd);
        d[c] = dd;
        m = fminf(m, dd);
    }

    unsigned mb = __float_as_uint(m);
    {   // pair-min (xor1 quad_perm): tau = max of 32 min-of-64 -> E[cnt]~130
        unsigned t = (unsigned)__builtin_amdgcn_update_dpp((int)mb, (int)mb,
                                                           0x0B1, 0xf, 0xf, false);
        mb = t < mb ? t : mb;
    }
    const unsigned tau = wave_umax_bcast(mb);
    const float tauf = __uint_as_float(tau);

    u64* cw = cand + wid * 256;
    unsigned base = 0;
    #pragma unroll
    for (int c = 0; c < 32; ++c) {
        const bool p = d[c] <= tauf;
        const u64 bm = __ballot(p);
        if (p) {
            unsigned off = base + (unsigned)__popcll(bm & ((1ull << lane) - 1ull));
            if (off < 256u)
                cw[off] = ((u64)__float_as_uint(d[c]) << 32) |
                          (unsigned)((c << 6) + lane);
        }
        base += (unsigned)__popcll(bm);
    }
    const u32 lim = (base > 256u) ? 0u : base;   // overflow -> all DEADK

    u64 k0 = ((u32)lane       < lim) ? cw[lane      ] : DEADK;
    u64 k1 = ((u32)lane + 64  < lim) ? cw[lane + 64 ] : DEADK;
    u64 k2 = ((u32)lane + 128 < lim) ? cw[lane + 128] : DEADK;
    u64 k3 = ((u32)lane + 192 < lim) ? cw[lane + 192] : DEADK;

#define CSWAP(a, b)                                                            \
  { u64 mn_ = (a) < (b) ? (a) : (b); u64 mx_ = (a) < (b) ? (b) : (a);          \
    (a) = mn_; (b) = mx_; }
    CSWAP(k0, k1) CSWAP(k2, k3) CSWAP(k0, k2) CSWAP(k1, k3) CSWAP(k1, k2)
#undef CSWAP

    u64 mykey = DEADK;
    for (int it = 0; it < K64; ++it) {
        u64 wm = wave_min64_l63(k0);
        u32 wlo = (u32)__builtin_amdgcn_readlane((int)(u32)wm, 63);
        u32 whi = (u32)__builtin_amdgcn_readlane((int)(u32)(wm >> 32), 63);
        if (whi == 0xFFFFFFFFu) break;
        const u64 wkey = ((u64)whi << 32) | wlo;
        mykey = (lane == it) ? wkey : mykey;
        const bool eq = (k0 == wkey);
        k0 = eq ? k1 : k0; k1 = eq ? k2 : k1; k2 = eq ? k3 : k2;
        k3 = eq ? DEADK : k3;
    }
    keys[row * (size_t)K64 + lane] = mykey;
}

// 8-wide batched segment probe: reads 8 u16 targets (one 16B LDS read) and
// 8 holder words (independent -> pipelined), builds alive/dead masks.
// Named scalars only (rule #20).
#define SEG_PROBE(LISTBASE, SEG, R)                                            \
    const uint4 w_ = *(const uint4*)&(LISTBASE)[(SEG)];                        \
    const u32 t0_ = w_.x & 0xFFFFu, t1_ = w_.x >> 16;                          \
    const u32 t2_ = w_.y & 0xFFFFu, t3_ = w_.y >> 16;                          \
    const u32 t4_ = w_.z & 0xFFFFu, t5_ = w_.z >> 16;                          \
    const u32 t6_ = w_.w & 0xFFFFu, t7_ = w_.w >> 16;                          \
    const u32 h0_ = holder[t0_ & (N - 1)], h1_ = holder[t1_ & (N - 1)];        \
    const u32 h2_ = holder[t2_ & (N - 1)], h3_ = holder[t3_ & (N - 1)];        \
    const u32 h4_ = holder[t4_ & (N - 1)], h5_ = holder[t5_ & (N - 1)];        \
    const u32 h6_ = holder[t6_ & (N - 1)], h7_ = holder[t7_ & (N - 1)];        \
    u32 am_ = 0, dm_ = 0;                                                      \
    if (t0_ == 0xFFFFu) dm_ |= 1u;   else if (h0_ > (R)) am_ |= 1u;            \
    if (t1_ == 0xFFFFu) dm_ |= 2u;   else if (h1_ > (R)) am_ |= 2u;            \
    if (t2_ == 0xFFFFu) dm_ |= 4u;   else if (h2_ > (R)) am_ |= 4u;            \
    if (t3_ == 0xFFFFu) dm_ |= 8u;   else if (h3_ > (R)) am_ |= 8u;            \
    if (t4_ == 0xFFFFu) dm_ |= 16u;  else if (h4_ > (R)) am_ |= 16u;           \
    if (t5_ == 0xFFFFu) dm_ |= 32u;  else if (h5_ > (R)) am_ |= 32u;           \
    if (t6_ == 0xFFFFu) dm_ |= 64u;  else if (h6_ > (R)) am_ |= 64u;           \
    if (t7_ == 0xFFFFu) dm_ |= 128u; else if (h7_ > (R)) am_ |= 128u;

#define SEG_TARGET(E)                                                          \
    ((E) < 2 ? ((E) & 1 ? t1_ : t0_)                                           \
             : (E) < 4 ? ((E) & 1 ? t3_ : t2_)                                 \
                       : (E) < 6 ? ((E) & 1 ? t5_ : t4_)                       \
                                 : ((E) & 1 ? t7_ : t6_))

// ---------------- Phase 2: da9 — batched-8 walks (da5 structure) -----------
// THEOREM (HW-validated R9-R19, absmax 0.0): greedy row-order matching ==
// unique stable matching == row-proposing DA under ANY proposal order;
// holder[] via atomicMin monotone => rejections permanent; total proposals
// Sum(k_r+1) is execution-order-INVARIANT (row r always proposes exactly to
// ranks 0..k_r). The ~440us wall (4 identical variants) = that fixed workload
// x per-rank dependent-LDS cost. da9 batches rank checks 8-wide: one 16B list
// read + 8 pipelined holder reads per segment (vs 2 dependent round-trips per
// rank). Skips (holder<r) permanent by monotonicity; atomicMin re-verifies;
// race -> re-read segment.
__global__ __launch_bounds__(1024, 1)
void emd_da9_kernel(const float* __restrict__ pred,
                    const float* __restrict__ target,
                    const u64* __restrict__ keys,
                    float* __restrict__ batch_emd) {
    __shared__ float tx[N], ty[N], tz[N];        // 24KB targets
    __shared__ float px[N], py[N], pz[N];        // 24KB preds
    __shared__ u32 holder[N];                    // 8KB
    __shared__ u16 posn[N];                      // 4KB
    __shared__ u16 list16[N * LE];               // 64KB u16 target lists
    __shared__ u16 exq[EXQ];                     // 4KB event ring
    __shared__ u32 talloc, head;
    __shared__ double dsum[1024];                // 8KB

    const int tid = threadIdx.x;
    const int lane = tid & 63;
    const int b = blockIdx.x;
    const float* pb = pred + (size_t)b * N * 3;
    const float* tb = target + (size_t)b * N * 3;
    const u64* kb = keys + (size_t)b * N * (size_t)K64;

    // ---- setup ----
    for (int idx = tid; idx < 3 * N; idx += 1024) {
        float vp = pb[idx], vt = tb[idx];
        int n = idx / 3, c = idx - 3 * n;
        if (c == 0)      { px[n] = vp; tx[n] = vt; }
        else if (c == 1) { py[n] = vp; ty[n] = vt; }
        else             { pz[n] = vp; tz[n] = vt; }
    }
    for (int j = tid; j < N; j += 1024) { holder[j] = INV; posn[j] = 0; }
    if (tid == 0) { talloc = 0; head = 0; }
    for (int idx = tid; idx < N * LE; idx += 1024) {
        const int row = idx >> 4, e = idx & (LE - 1);
        const u64 key = kb[(size_t)row * K64 + e];
        list16[idx] = ((u32)(key >> 32) == INV) ? (u16)0xFFFF
                                                : (u16)((u32)key & (N - 1));
    }
    __syncthreads();

    // ---- stage 1: per-thread batched walks with adoption ----
    #pragma unroll
    for (int k = 0; k < 2; ++k) {
        u32 r = (u32)tid + (k ? 1024u : 0u);
        u32 p = 0;
        for (int guard = 0; guard < 200000; ++guard) {
            if (p >= LE) {              // deep walk -> defer to stage 2
                posn[r] = LE;
                const u32 s = atomicAdd(&talloc, 1u);
                exq[s & (EXQ - 1)] = (u16)r;
                break;
            }
            const u32 seg = p & ~7u;
            SEG_PROBE(list16 + (r << 4), seg, r)
            const u32 lv = 0xFFu & ~((1u << (p - seg)) - 1u);
            const u32 evm = (am_ | dm_) & lv;
            if (!evm) { p = seg + 8; continue; }
            const u32 e = (u32)__builtin_ctz(evm);
            if (dm_ & (1u << e)) {      // dead suffix -> overflow row
                posn[r] = 64;
                const u32 s = atomicAdd(&talloc, 1u);
                exq[s & (EXQ - 1)] = (u16)r;
                break;
            }
            const u32 t = SEG_TARGET(e);
            const u32 old = atomicMin(&holder[t], r);
            if (old < r) { p = seg + e + 1; continue; }   // raced: retry
            posn[r] = (u16)(seg + e + 1);                 // held
            if (old == INV) break;                        // chain done
            r = old; p = (u32)posn[r];                    // ADOPT
        }
    }
    __syncthreads();

    // ---- stage 2: frozen event list; batched hops, wave-level deep path ---
    {
        const u32 TA = talloc;          // frozen: stage 2 never pushes
        for (int guard = 0; guard < 20000; ++guard) {
            u32 i = 0;
            if (lane == 0) i = atomicAdd(&head, 1u);
            i = (u32)__builtin_amdgcn_readlane((int)i, 0);
            if (i >= TA) break;
            u32 r = (u32)exq[i & (EXQ - 1)];         // uniform LDS read

            for (int cg = 0; cg < 200000; ++cg) {    // cascade with adoption
                u32 p = (u32)posn[r];                // uniform
                u32 nextr = INV;
                bool matched_free = false, resolved = false;

                // A) batched walk over list16 entries p..15 (wave-uniform)
                for (int w8 = 0; w8 < 24 && !resolved; ++w8) {
                    if (p >= LE) break;
                    const u32 seg = p & ~7u;
                    SEG_PROBE(list16 + (r << 4), seg, r)
                    const u32 lv = 0xFFu & ~((1u << (p - seg)) - 1u);
                    const u32 evm = (am_ | dm_) & lv;
                    if (!evm) { p = seg + 8; continue; }
                    const u32 e = (u32)__builtin_ctz(evm);
                    if (dm_ & (1u << e)) { p = 64; break; }  // dead suffix
                    const u32 t = SEG_TARGET(e);
                    u32 old = 0;
                    if (lane == 0) old = atomicMin(&holder[t], r);
                    old = (u32)__builtin_amdgcn_readlane((int)old, 0);
                    if (old < r) { p = seg + e + 1; continue; }   // raced
                    if (lane == 0) posn[r] = (u16)(seg + e + 1);
                    resolved = true;
                    if (old == INV) matched_free = true; else nextr = old;
                }
                if (!resolved && lane == 0) posn[r] = (u16)p;

                // B) wave-level global top-64 resume: entries p..63
                if (!resolved && p < 64) {
                    const u64 key = kb[(size_t)r * K64 + lane];
                    const u32 dv = (u32)(key >> 32);
                    const u32 t = (u32)key & (N - 1);
                    const bool cand = ((u32)lane >= p) && (dv != INV) &&
                                      (holder[t] > r);
                    u64 bal = __ballot(cand);
                    while (bal) {                    // propose in list order
                        const int L = __ffsll((long long)bal) - 1;
                        const u32 tL = (u32)__builtin_amdgcn_readlane((int)t, L);
                        u32 old = 0;
                        if (lane == 0) old = atomicMin(&holder[tL], r);
                        old = (u32)__builtin_amdgcn_readlane((int)old, 0);
                        if (old > r) {
                            if (lane == 0) posn[r] = (u16)(L + 1);
                            resolved = true;
                            if (old == INV) matched_free = true;
                            else nextr = old;
                            break;
                        }
                        bal &= ~(1ull << (u32)L);    // raced: permanent
                    }
                }

                // C) wave-level full scan over {j: holder[j]>r}; DISTs hoisted
                if (!resolved) {
                    const float qx = px[r], qy = py[r], qz = pz[r];
                    u32 dbits[32];
                    #pragma unroll
                    for (int c = 0; c < 32; ++c) {
                        const int j = (c << 6) + lane;
                        float dd;
                        DIST(qx, qy, qz, tx, ty, tz, j, dd);
                        dbits[c] = __float_as_uint(dd);
                    }
                    for (int rty = 0; rty < 100000; ++rty) {
                        u64 best = DEADK;
                        #pragma unroll 8
                        for (int c = 0; c < 32; ++c) {
                            const int j = (c << 6) + lane;
                            if (holder[j] > r) {
                                const u64 kk = ((u64)dbits[c] << 32) | (u32)j;
                                if (kk < best) best = kk;
                            }
                        }
                        const u64 wm = wave_min64_l63(best);
                        const u32 jw =
                            (u32)__builtin_amdgcn_readlane((int)(u32)wm, 63) &
                            (N - 1);
                        u32 old = 0;
                        if (lane == 0) old = atomicMin(&holder[jw], r);
                        old = (u32)__builtin_amdgcn_readlane((int)old, 0);
                        if (old < r) continue;       // lost race: set shrank
                        if (lane == 0) posn[r] = 64;
                        if (old == INV) matched_free = true; else nextr = old;
                        break;
                    }
                }

                if (matched_free) break;             // cascade ended
                r = nextr;                           // adopt, continue
            }
        }
    }
    __syncthreads();

    // ---- final sum over targets (recomputed DIST bit-identical to keys) ---
    double s = 0.0;
    #pragma unroll
    for (int k = 0; k < 2; ++k) {
        const int t = tid + (k ? 1024 : 0);
        const u32 r = holder[t] & (N - 1);
        float dd;
        DIST(px[r], py[r], pz[r], tx, ty, tz, t, dd);
        s += (double)dd;
    }
    dsum[tid] = s;
    __syncthreads();
    for (int st = 512; st >= 1; st >>= 1) {
        if (tid < st) dsum[tid] += dsum[tid + st];
        __syncthreads();
    }
    if (tid == 0) batch_emd[b] = (float)(dsum[0] / N);
}

// ---------------- exact full-scan helper (tiny-ws fallback kernel) --------
__device__ __forceinline__ u64 full_scan_row(
    int lane, float qx, float qy, float qz,
    const float* tx, const float* ty, const float* tz,
    const unsigned char* used) {
  u32 dl = 0xFFFFFFFFu, jl = 0u;
  #pragma unroll 8
  for (int c = 0; c < 32; ++c) {
    const int j = (c << 6) + lane;
    if (!used[j]) {
      float dd;
      DIST(qx, qy, qz, tx, ty, tz, j, dd);
      const u32 db = __float_as_uint(dd);
      if (db < dl) { dl = db; jl = (u32)j; }
    }
  }
  const u32 dmin = wave_umin_bcast(dl);
  const u32 jc = (dl == dmin) ? jl : 0xFFFFFFFFu;
  const u32 jmin = wave_umin_bcast(jc);
  return ((u64)dmin << 32) | jmin;
}

__global__ __launch_bounds__(64, 1)
void emd_greedy_full_kernel(const float* __restrict__ pred,
                            const float* __restrict__ target,
                            float* __restrict__ batch_emd) {
    __shared__ float tx[N], ty[N], tz[N];
    __shared__ float qxs[N], qys[N], qzs[N];
    __shared__ unsigned char used[N];

    const int lane = threadIdx.x;
    const int b = blockIdx.x;
    const float* pb = pred + (size_t)b * N * 3;
    const float* tb = target + (size_t)b * N * 3;

    for (int idx = lane; idx < 3 * N; idx += 64) {
        float vp = pb[idx], vt = tb[idx];
        int n = idx / 3, c = idx - 3 * n;
        if (c == 0)      { qxs[n] = vp; tx[n] = vt; }
        else if (c == 1) { qys[n] = vp; ty[n] = vt; }
        else             { qzs[n] = vp; tz[n] = vt; }
    }
    for (int j = lane; j < N; j += 64) used[j] = 0;

    double sum = 0.0;
    for (int i = 0; i < N; ++i) {
        u64 fs = full_scan_row(lane, qxs[i], qys[i], qzs[i], tx, ty, tz, used);
        sum += (double)__uint_as_float((u32)(fs >> 32));
        if (lane == 0) used[(u32)fs] = 1;
    }
    if (lane == 0) batch_emd[b] = (float)(sum / N);
}

__global__ void emd_mean_kernel(const float* __restrict__ batch_emd,
                                float* __restrict__ out) {
    double s = 0.0;
    for (int b = 0; b < BATCH; ++b) s += (double)batch_emd[b];
    out[0] = (float)(s / BATCH);
}

extern "C" void kernel_launch(void* const* d_in, const int* in_sizes, int n_in,
                              void* d_out, int out_size, void* d_ws, size_t ws_size,
                              hipStream_t stream) {
    const float* pred   = (const float*)d_in[0];
    const float* target = (const float*)d_in[1];
    float* out = (float*)d_out;
    char* wsb = (char*)d_ws;

    const size_t keysz = (size_t)NROWS * K64 * 8;   // 8.4 MB
    if (ws_size >= keysz + 64) {
        u64* keys = (u64*)wsb;
        float* emd = (float*)(wsb + keysz);
        emd_shortsort_kernel<<<NROWS / 4, 256, 0, stream>>>(pred, target, keys);
        emd_da9_kernel<<<BATCH, 1024, 0, stream>>>(pred, target, keys, emd);
        emd_mean_kernel<<<1, 1, 0, stream>>>(emd, out);
    } else {
        float* emd = (float*)wsb;
        emd_greedy_full_kernel<<<BATCH, 64, 0, stream>>>(pred, target, emd);
        emd_mean_kernel<<<1, 1, 0, stream>>>(emd, out);
    }
}